// Round 1
// baseline (841.815 us; speedup 1.0000x reference)
//
#include <hip/hip_runtime.h>
#include <cstdio>
#include <cstdint>

typedef _Float16 f16;
typedef _Float16 f16x4 __attribute__((ext_vector_type(4)));
typedef _Float16 f16x8 __attribute__((ext_vector_type(8)));
typedef float f32x4 __attribute__((ext_vector_type(4)));

#define GLL16(gp, lp)                                                          \
  __builtin_amdgcn_global_load_lds(                                            \
      (const __attribute__((address_space(1))) void*)(gp),                     \
      (__attribute__((address_space(3))) void*)(lp), 16, 0, 0)

// ---------------- fp32 -> fp16 elementwise (h) ----------------
__global__ void cvt_f32_f16_kernel(const float* __restrict__ in,
                                   f16* __restrict__ out, int n4) {
  int i = blockIdx.x * blockDim.x + threadIdx.x;
  if (i < n4) {
    float4 v = reinterpret_cast<const float4*>(in)[i];
    f16x4 o;
    o[0] = (f16)v.x; o[1] = (f16)v.y; o[2] = (f16)v.z; o[3] = (f16)v.w;
    reinterpret_cast<f16x4*>(out)[i] = o;
  }
}

// ---------------- fp32 (R x C) -> fp16 transposed (C x R), 9 slots ----------
// slot < nA: src = inA + slot*R*C ; slot >= nA: src = inB (the shared weight)
__global__ void tr_cvt_kernel(const float* __restrict__ inA,
                              const float* __restrict__ inB,
                              f16* __restrict__ out, int R, int C, int nA) {
  int slot = blockIdx.z;
  const float* src = (slot < nA) ? (inA + (size_t)slot * R * C) : inB;
  f16* dst = out + (size_t)slot * R * C;
  __shared__ float tile[32][33];
  int tx = threadIdx.x, ty = threadIdx.y;
  int c = blockIdx.x * 32 + tx;
#pragma unroll
  for (int j = 0; j < 4; ++j) {
    int r = blockIdx.y * 32 + ty + j * 8;
    tile[ty + j * 8][tx] = src[(size_t)r * C + c];
  }
  __syncthreads();
  int oc = blockIdx.y * 32 + tx;
#pragma unroll
  for (int j = 0; j < 4; ++j) {
    int orr = blockIdx.x * 32 + ty + j * 8;
    dst[(size_t)orr * R + oc] = (f16)tile[tx][ty + j * 8];
  }
}

// ---------------- 128x128 tile GEMM (m97 structure), fp16 MFMA --------------
// C[m][n] = sum_k A[m][k] * Bt[n][k]
// MODE 0: T[m][slot*4096+n] = C                     (pass U)
// MODE 1: T[idx] = silu(C) * T[idx] * coef(slot,b)  (pass G)
// MODE 2: P[slot][m][n] = C                          (pass D, split-K partials)
template <int MODE>
__global__ void gemm128_kernel(const f16* __restrict__ A, int lda, long aSlotOff,
                               const f16* __restrict__ Bt, int ldb, int kIters,
                               f16* __restrict__ T,
                               const float* __restrict__ gate,
                               const float* __restrict__ sgp,
                               float* __restrict__ P) {
  int nt = blockIdx.x, mt = blockIdx.y, slot = blockIdx.z;
  __shared__ __align__(16) f16 As[4096];  // [128 rows][32 k]
  __shared__ __align__(16) f16 Bs[4096];  // [128 cols][32 k]
  int t = threadIdx.x, w = t >> 6, l = t & 63;

  const f16* Ab = A + (size_t)slot * (size_t)aSlotOff;
  const f16* Bb = Bt + (size_t)slot * (size_t)(4096ll * 1024);

  // staging: thread t copies 16B; LDS dest = wave-uniform base + lane*16
  const f16* gA0 = Ab + (size_t)(mt * 128 + w * 16 + (l >> 2)) * lda + (l & 3) * 8;
  const f16* gA1 = gA0 + (size_t)64 * lda;
  const f16* gB0 = Bb + (size_t)(nt * 128 + w * 16 + (l >> 2)) * ldb + (l & 3) * 8;
  const f16* gB1 = gB0 + (size_t)64 * ldb;
  f16* lA0 = &As[w * 512];
  f16* lA1 = &As[2048 + w * 512];
  f16* lB0 = &Bs[w * 512];
  f16* lB1 = &Bs[2048 + w * 512];

  int wr = w >> 1, wc = w & 1;
  int lrow = l & 15, lkb = (l >> 4) * 8;

  f32x4 acc[4][4] = {};

  for (int kt = 0; kt < kIters; ++kt) {
    if (kt) __syncthreads();
    int ko = kt * 32;
    GLL16(gA0 + ko, lA0);
    GLL16(gA1 + ko, lA1);
    GLL16(gB0 + ko, lB0);
    GLL16(gB1 + ko, lB1);
    __syncthreads();

    f16x8 aF[4], bF[4];
#pragma unroll
    for (int mi = 0; mi < 4; ++mi)
      aF[mi] = *reinterpret_cast<const f16x8*>(
          &As[(wr * 64 + mi * 16 + lrow) * 32 + lkb]);
#pragma unroll
    for (int ni = 0; ni < 4; ++ni)
      bF[ni] = *reinterpret_cast<const f16x8*>(
          &Bs[(wc * 64 + ni * 16 + lrow) * 32 + lkb]);
#pragma unroll
    for (int mi = 0; mi < 4; ++mi)
#pragma unroll
      for (int ni = 0; ni < 4; ++ni)
        acc[mi][ni] = __builtin_amdgcn_mfma_f32_16x16x32_f16(
            aF[mi], bF[ni], acc[mi][ni], 0, 0, 0);
  }

  // epilogue: C/D layout col = lane&15, row = (lane>>4)*4 + j
  int r0 = (l >> 4) * 4, c0 = l & 15;
  float coef = 0.f;
  if (MODE == 1) {
    int b = (mt * 128) >> 10;  // all 128 rows of this block share b
    float s = sgp[b];
    coef = (slot < 8) ? (1.f - s) * gate[b * 8 + slot] : s;
  }
#pragma unroll
  for (int mi = 0; mi < 4; ++mi) {
#pragma unroll
    for (int ni = 0; ni < 4; ++ni) {
#pragma unroll
      for (int j = 0; j < 4; ++j) {
        int grow = mt * 128 + wr * 64 + mi * 16 + r0 + j;
        int gcol = nt * 128 + wc * 64 + ni * 16 + c0;
        float v = acc[mi][ni][j];
        if (MODE == 0) {
          T[(size_t)grow * 36864 + slot * 4096 + gcol] = (f16)v;
        } else if (MODE == 1) {
          size_t idx = (size_t)grow * 36864 + slot * 4096 + gcol;
          float u = (float)T[idx];
          float sil = v / (1.f + __expf(-v));
          T[idx] = (f16)(sil * u * coef);
        } else {
          P[((size_t)slot << 21) + (size_t)grow * 1024 + gcol] = v;
        }
      }
    }
  }
}

// ---------------- sum 9 split-K partials -> fp32 out ------------------------
__global__ void reduce9_kernel(const float* __restrict__ P,
                               float* __restrict__ out, int n4) {
  int i = blockIdx.x * blockDim.x + threadIdx.x;
  if (i < n4) {
    float4 s = {0.f, 0.f, 0.f, 0.f};
#pragma unroll
    for (int e = 0; e < 9; ++e) {
      float4 v = reinterpret_cast<const float4*>(P + ((size_t)e << 21))[i];
      s.x += v.x; s.y += v.y; s.z += v.z; s.w += v.w;
    }
    reinterpret_cast<float4*>(out)[i] = s;
  }
}

extern "C" void kernel_launch(void* const* d_in, const int* in_sizes, int n_in,
                              void* d_out, int out_size, void* d_ws,
                              size_t ws_size, hipStream_t stream) {
  const float* h    = (const float*)d_in[0];
  const float* gate = (const float*)d_in[1];
  const float* sgp  = (const float*)d_in[2];
  const float* Wg   = (const float*)d_in[3];
  const float* Wu   = (const float*)d_in[4];
  const float* Wd   = (const float*)d_in[5];
  const float* Sg   = (const float*)d_in[6];
  const float* Su   = (const float*)d_in[7];
  const float* Sd   = (const float*)d_in[8];

  // ws layout (bytes)
  const size_t SZ_HB = 4194304;      // 2048*1024 f16
  const size_t SZ_W  = 75497472;     // 9*4096*1024 f16
  const size_t SZ_T  = 150994944;    // 2048*36864 f16
  const size_t SZ_P  = 75497472;     // 9*2048*1024 f32
  char* ws = (char*)d_ws;
  f16*   hb  = (f16*)(ws);
  f16*   WgT = (f16*)(ws + SZ_HB);
  f16*   WuT = (f16*)(ws + SZ_HB + SZ_W);
  f16*   WdT = (f16*)(ws + SZ_HB + 2 * SZ_W);
  f16*   T   = (f16*)(ws + SZ_HB + 3 * SZ_W);
  float* P   = (float*)(ws + SZ_HB + 3 * SZ_W + SZ_T);
  size_t need = SZ_HB + 3 * SZ_W + SZ_T + SZ_P;
  if (ws_size < need) {
    fprintf(stderr, "kernel_launch: ws too small (%zu < %zu)\n", ws_size, need);
    return;
  }
  float* out = (float*)d_out;

  // 1) converts / transposes to fp16 B^T layouts
  cvt_f32_f16_kernel<<<2048, 256, 0, stream>>>(h, hb, 524288);
  tr_cvt_kernel<<<dim3(128, 32, 9), dim3(32, 8), 0, stream>>>(Wg, Sg, WgT, 1024, 4096, 8);
  tr_cvt_kernel<<<dim3(128, 32, 9), dim3(32, 8), 0, stream>>>(Wu, Su, WuT, 1024, 4096, 8);
  tr_cvt_kernel<<<dim3(32, 128, 9), dim3(32, 8), 0, stream>>>(Wd, Sd, WdT, 4096, 1024, 8);

  // 2) pass U: T = h @ Wu   (per slot)
  gemm128_kernel<0><<<dim3(32, 16, 9), 256, 0, stream>>>(
      hb, 1024, 0, WuT, 1024, 32, T, nullptr, nullptr, nullptr);
  // 3) pass G: T = silu(h @ Wg) * T * coef
  gemm128_kernel<1><<<dim3(32, 16, 9), 256, 0, stream>>>(
      hb, 1024, 0, WgT, 1024, 32, T, gate, sgp, nullptr);
  // 4) pass D: P[slot] = T[:, slot] @ Wd[slot]   (split-K over 9 slots)
  gemm128_kernel<2><<<dim3(8, 16, 9), 256, 0, stream>>>(
      T, 36864, 4096, WdT, 4096, 128, nullptr, nullptr, nullptr, P);
  // 5) reduce partials -> out
  reduce9_kernel<<<2048, 256, 0, stream>>>(P, out, 524288);
}